// Round 2
// baseline (269.608 us; speedup 1.0000x reference)
//
#include <hip/hip_runtime.h>

// Problem constants: B=8, H=W=1024, V=35709, T=70789
#define BATCH 8
#define HWPIX (1024 * 1024)
#define NVERT 35709
#define NTRI  70789

typedef float        f32x4 __attribute__((ext_vector_type(4)));
typedef int          i32x4 __attribute__((ext_vector_type(4)));
typedef unsigned int u32x4 __attribute__((ext_vector_type(4)));

__device__ __forceinline__ unsigned q8(float x) {
    float v = x * 255.0f + 0.5f;
    v = fminf(fmaxf(v, 0.0f), 255.0f);
    return (unsigned)v;
}

// ---------------------------------------------------------------------------
// Prep stage 1: per-(batch,vertex) RGBX u8 color in one uint. ctab: [B,V].
// ---------------------------------------------------------------------------
__global__ __launch_bounds__(256) void quant_colors(
    const float* __restrict__ colors,   // [B,V,3]
    unsigned*    __restrict__ ctab)     // [B,V]
{
    const int v = blockIdx.x * blockDim.x + threadIdx.x;
    const int b = blockIdx.y;
    if (v >= NVERT) return;
    const float* c = colors + ((long long)b * NVERT + v) * 3;
    ctab[b * NVERT + v] = q8(c[0]) | (q8(c[1]) << 8) | (q8(c[2]) << 16);
}

// ---------------------------------------------------------------------------
// Prep stage 2: per-(batch,triangle) record = (rgbx0, rgbx1, rgbx2, 0) uint4.
// tab: [B,T] = 9.06 MB (1.13 MB/batch, L2-resident; blockIdx&7 batch slicing
// maps one batch per XCD so each XCD's L2 holds only its slice).
// ---------------------------------------------------------------------------
__global__ __launch_bounds__(256) void build_tab(
    const int*      __restrict__ tris,  // [T,3]
    const unsigned* __restrict__ ctab,  // [B,V]
    u32x4*          __restrict__ tab)   // [B,T]
{
    const int t = blockIdx.x * blockDim.x + threadIdx.x;
    const int b = blockIdx.y;
    if (t >= NTRI) return;
    const int v0 = tris[3 * t + 0];
    const int v1 = tris[3 * t + 1];
    const int v2 = tris[3 * t + 2];
    const unsigned* cb = ctab + b * NVERT;
    u32x4 w;
    w.x = cb[v0]; w.y = cb[v1]; w.z = cb[v2]; w.w = 0u;
    tab[(long long)b * NTRI + t] = w;
}

// ---------------------------------------------------------------------------
// Main (R7 shape, sc0 A/B): 4096 blocks, one thread = 2 quads 256 apart
// (coalesced 16B/lane streams, 8 px). Record gathers issued as ONE inline-asm
// block of plain cached global_load_dwordx4 (this round: sc0 REMOVED to
// isolate whether the agent-scope bypass path throttles the random-request
// service rate; everything else byte-identical to the 269.5 µs baseline).
// All outputs are EARLY-CLOBBER (=&v) so result VGPRs can never alias a
// not-yet-consumed address pair. Block ends with s_waitcnt vmcnt(0); earlier
// tid/bary loads are drained by the same wait.
// ---------------------------------------------------------------------------
__global__ __launch_bounds__(256) void raster_sc0_kernel(
    const int*   __restrict__ tids,   // [B,H,W]
    const float* __restrict__ bary,   // [B,H,W,3]
    const u32x4* __restrict__ tab,    // [B,T]
    float*       __restrict__ out)    // images [B,3,H,W] ++ alphas [B,1,H,W]
{
    const int b   = blockIdx.x & 7;              // batch slice (1 batch/XCD)
    const int blk = blockIdx.x >> 3;             // 0..511 within batch
    const int tid = (int)threadIdx.x;
    const int q0  = blk * 512 + tid;             // quad index in batch (u=0)
    const long long qg0 = (long long)b * (HWPIX / 4) + q0;

    // Coalesced cached loads: 2 x int4 tids, 6 x float4 bary
    i32x4 t4[2];
    t4[0] = ((const i32x4*)tids)[qg0];
    t4[1] = ((const i32x4*)tids)[qg0 + 256];
    f32x4 bv[6];
#pragma unroll
    for (int u = 0; u < 2; ++u)
#pragma unroll
        for (int k = 0; k < 3; ++k)
            bv[3 * u + k] = ((const f32x4*)bary)[(qg0 + u * 256) * 3 + k];

    // 8 independent cached gathers in one asm block (early-clobber outs).
    const u32x4* tbp = tab + (long long)b * NTRI;
    const u32x4* p0 = tbp + t4[0].x;
    const u32x4* p1 = tbp + t4[0].y;
    const u32x4* p2 = tbp + t4[0].z;
    const u32x4* p3 = tbp + t4[0].w;
    const u32x4* p4 = tbp + t4[1].x;
    const u32x4* p5 = tbp + t4[1].y;
    const u32x4* p6 = tbp + t4[1].z;
    const u32x4* p7 = tbp + t4[1].w;
    u32x4 r0, r1, r2, r3, r4, r5, r6, r7;
    asm volatile(
        "global_load_dwordx4 %0, %8,  off\n\t"
        "global_load_dwordx4 %1, %9,  off\n\t"
        "global_load_dwordx4 %2, %10, off\n\t"
        "global_load_dwordx4 %3, %11, off\n\t"
        "global_load_dwordx4 %4, %12, off\n\t"
        "global_load_dwordx4 %5, %13, off\n\t"
        "global_load_dwordx4 %6, %14, off\n\t"
        "global_load_dwordx4 %7, %15, off\n\t"
        "s_waitcnt vmcnt(0)"
        : "=&v"(r0), "=&v"(r1), "=&v"(r2), "=&v"(r3),
          "=&v"(r4), "=&v"(r5), "=&v"(r6), "=&v"(r7)
        : "v"(p0), "v"(p1), "v"(p2), "v"(p3),
          "v"(p4), "v"(p5), "v"(p6), "v"(p7)
        : "memory");
    const u32x4 rec[8] = {r0, r1, r2, r3, r4, r5, r6, r7};

    float* img = out + (long long)b * (3 * HWPIX);
    float* al  = out + (long long)BATCH * 3 * HWPIX + (long long)b * HWPIX;

#pragma unroll
    for (int u = 0; u < 2; ++u) {
        const f32x4 b0 = bv[3 * u + 0], b1 = bv[3 * u + 1], b2 = bv[3 * u + 2];
        const float w0[4] = {b0.x, b0.w, b1.z, b2.y};
        const float w1[4] = {b0.y, b1.x, b1.w, b2.z};
        const float w2[4] = {b0.z, b1.y, b2.x, b2.w};

        float r[4], g[4], bl[4], a[4];
#pragma unroll
        for (int i = 0; i < 4; ++i) {
            const u32x4 w = rec[4 * u + i];
            const float s0 = w0[i] * (1.0f / 255.0f);
            const float s1 = w1[i] * (1.0f / 255.0f);
            const float s2 = w2[i] * (1.0f / 255.0f);
            r[i]  = fminf(fmaxf((float)( w.x        & 0xff) * s0 +
                                (float)( w.y        & 0xff) * s1 +
                                (float)( w.z        & 0xff) * s2, 0.0f), 1.0f);
            g[i]  = fminf(fmaxf((float)((w.x >>  8) & 0xff) * s0 +
                                (float)((w.y >>  8) & 0xff) * s1 +
                                (float)((w.z >>  8) & 0xff) * s2, 0.0f), 1.0f);
            bl[i] = fminf(fmaxf((float)((w.x >> 16) & 0xff) * s0 +
                                (float)((w.y >> 16) & 0xff) * s1 +
                                (float)((w.z >> 16) & 0xff) * s2, 0.0f), 1.0f);
            a[i]  = fminf(fmaxf(2.0f * (w0[i] + w1[i] + w2[i]), 0.0f), 1.0f);
        }

        const long long s = q0 + u * 256;
        f32x4 vr = {r[0],  r[1],  r[2],  r[3]};
        f32x4 vg = {g[0],  g[1],  g[2],  g[3]};
        f32x4 vb = {bl[0], bl[1], bl[2], bl[3]};
        f32x4 va = {a[0],  a[1],  a[2],  a[3]};
        __builtin_nontemporal_store(vr, ((f32x4*)(img            )) + s);
        __builtin_nontemporal_store(vg, ((f32x4*)(img +     HWPIX)) + s);
        __builtin_nontemporal_store(vb, ((f32x4*)(img + 2 * HWPIX)) + s);
        __builtin_nontemporal_store(va, ((f32x4*)(al             )) + s);
    }
}

// ---------------------------------------------------------------------------
// Fallback: direct two-level gather (R1), used only if ws is too small.
// ---------------------------------------------------------------------------
__global__ __launch_bounds__(256) void raster_kernel(
    const int*   __restrict__ tids,
    const float* __restrict__ bary,
    const float* __restrict__ colors,
    const int*   __restrict__ tris,
    float*       __restrict__ out)
{
    const long long q  = (long long)blockIdx.x * blockDim.x + threadIdx.x;
    const long long p0 = q << 2;
    const int b  = (int)(p0 >> 20);
    const int hw = (int)(p0 & (HWPIX - 1));

    const int4 t4 = ((const int4*)tids)[q];
    const float4 bv0 = ((const float4*)bary)[q * 3 + 0];
    const float4 bv1 = ((const float4*)bary)[q * 3 + 1];
    const float4 bv2 = ((const float4*)bary)[q * 3 + 2];

    const float w0[4] = {bv0.x, bv0.w, bv1.z, bv2.y};
    const float w1[4] = {bv0.y, bv1.x, bv1.w, bv2.z};
    const float w2[4] = {bv0.z, bv1.y, bv2.x, bv2.w};
    const int  tid[4] = {t4.x, t4.y, t4.z, t4.w};

    const float* __restrict__ cb = colors + (long long)b * (3 * NVERT);

    float r[4], g[4], bl[4], a[4];
#pragma unroll
    for (int i = 0; i < 4; ++i) {
        const int t  = tid[i];
        const int v0 = tris[3 * t + 0];
        const int v1 = tris[3 * t + 1];
        const int v2 = tris[3 * t + 2];
        const float* c0 = cb + 3 * v0;
        const float* c1 = cb + 3 * v1;
        const float* c2 = cb + 3 * v2;
        const float u0 = w0[i], u1 = w1[i], u2 = w2[i];
        r[i]  = fminf(fmaxf(c0[0] * u0 + c1[0] * u1 + c2[0] * u2, 0.0f), 1.0f);
        g[i]  = fminf(fmaxf(c0[1] * u0 + c1[1] * u1 + c2[1] * u2, 0.0f), 1.0f);
        bl[i] = fminf(fmaxf(c0[2] * u0 + c1[2] * u1 + c2[2] * u2, 0.0f), 1.0f);
        a[i]  = fminf(fmaxf(2.0f * (u0 + u1 + u2), 0.0f), 1.0f);
    }

    float* img = out + (long long)b * (3 * HWPIX) + hw;
    ((float4*)(img            ))[0] = make_float4(r[0],  r[1],  r[2],  r[3]);
    ((float4*)(img +     HWPIX))[0] = make_float4(g[0],  g[1],  g[2],  g[3]);
    ((float4*)(img + 2 * HWPIX))[0] = make_float4(bl[0], bl[1], bl[2], bl[3]);

    float* al = out + (long long)BATCH * 3 * HWPIX + (long long)b * HWPIX + hw;
    ((float4*)al)[0] = make_float4(a[0], a[1], a[2], a[3]);
}

extern "C" void kernel_launch(void* const* d_in, const int* in_sizes, int n_in,
                              void* d_out, int out_size, void* d_ws, size_t ws_size,
                              hipStream_t stream) {
    const int*   tids   = (const int*)  d_in[0];
    const float* bary   = (const float*)d_in[1];
    const float* colors = (const float*)d_in[2];
    const int*   tris   = (const int*)  d_in[3];
    float*       out    = (float*)      d_out;

    const size_t tab_bytes  = (size_t)BATCH * NTRI * sizeof(u32x4);     // ~9.06 MB
    const size_t ctab_bytes = (size_t)BATCH * NVERT * sizeof(unsigned); // ~1.14 MB

    if (ws_size >= tab_bytes + ctab_bytes) {
        u32x4*    tab  = (u32x4*)d_ws;
        unsigned* ctab = (unsigned*)((char*)d_ws + tab_bytes);

        dim3 g1((NVERT + 255) / 256, BATCH, 1);
        quant_colors<<<g1, 256, 0, stream>>>(colors, ctab);

        dim3 g2((NTRI + 255) / 256, BATCH, 1);
        build_tab<<<g2, 256, 0, stream>>>(tris, ctab, tab);

        const int grid = (BATCH * HWPIX) / (8 * 256);   // 4096 blocks
        raster_sc0_kernel<<<grid, 256, 0, stream>>>(tids, bary, tab, out);
    } else {
        const int quads = (BATCH * HWPIX) / 4;
        raster_kernel<<<quads / 256, 256, 0, stream>>>(tids, bary, colors, tris, out);
    }
}

// Round 3
// 265.158 us; speedup vs baseline: 1.0168x; 1.0168x over previous
//
#include <hip/hip_runtime.h>

// Problem constants: B=8, H=W=1024, V=35709, T=70789
#define BATCH 8
#define HWPIX (1024 * 1024)
#define NVERT 35709
#define NTRI  70789

typedef float        f32x4 __attribute__((ext_vector_type(4)));
typedef int          i32x4 __attribute__((ext_vector_type(4)));
typedef unsigned int u32x4 __attribute__((ext_vector_type(4)));

__device__ __forceinline__ unsigned q8(float x) {
    float v = x * 255.0f + 0.5f;
    v = fminf(fmaxf(v, 0.0f), 255.0f);
    return (unsigned)v;
}

// ---------------------------------------------------------------------------
// Prep stage 1 (R3: transposed): one thread per VERTEX, loop over batches.
// ctab_t[v] = 8 x u32 (RGBX for b=0..7) = 32B contiguous per vertex, so the
// build stage fetches all 8 batches of one vertex in TWO 16B requests
// instead of 8 random 4B requests. Reads are lane-coalesced (consecutive v),
// writes are perfectly coalesced u32x4 pairs.
// ---------------------------------------------------------------------------
__global__ __launch_bounds__(256) void quant_colors_t(
    const float* __restrict__ colors,   // [B,V,3]
    u32x4*       __restrict__ ctab_t)   // [V,2] u32x4  (= [V][8] u32)
{
    const int v = blockIdx.x * blockDim.x + threadIdx.x;
    if (v >= NVERT) return;
    unsigned w[8];
#pragma unroll
    for (int b = 0; b < BATCH; ++b) {
        const float* c = colors + ((long long)b * NVERT + v) * 3;
        w[b] = q8(c[0]) | (q8(c[1]) << 8) | (q8(c[2]) << 16);
    }
    u32x4 lo = {w[0], w[1], w[2], w[3]};
    u32x4 hi = {w[4], w[5], w[6], w[7]};
    ctab_t[2 * v + 0] = lo;
    ctab_t[2 * v + 1] = hi;
}

// ---------------------------------------------------------------------------
// Prep stage 2 (R3: batch-fused): one thread per TRIANGLE, assembling the
// records for ALL 8 batches. Random-request count drops 24 -> 6 per triangle
// (3 vertices x 2 u32x4 loads), 1.7M -> 425K total. Stores: 8 coalesced 16B
// per thread (consecutive t -> consecutive tab entries per batch plane).
// ---------------------------------------------------------------------------
__global__ __launch_bounds__(256) void build_tab_t(
    const int*   __restrict__ tris,     // [T,3]
    const u32x4* __restrict__ ctab_t,   // [V,2]
    u32x4*       __restrict__ tab)      // [B,T]
{
    const int t = blockIdx.x * blockDim.x + threadIdx.x;
    if (t >= NTRI) return;
    const int v0 = tris[3 * t + 0];
    const int v1 = tris[3 * t + 1];
    const int v2 = tris[3 * t + 2];

    // 6 independent 16B gathers (compiler schedules them back-to-back).
    const u32x4 c0lo = ctab_t[2 * v0 + 0], c0hi = ctab_t[2 * v0 + 1];
    const u32x4 c1lo = ctab_t[2 * v1 + 0], c1hi = ctab_t[2 * v1 + 1];
    const u32x4 c2lo = ctab_t[2 * v2 + 0], c2hi = ctab_t[2 * v2 + 1];

    const unsigned a0[8] = {c0lo.x, c0lo.y, c0lo.z, c0lo.w, c0hi.x, c0hi.y, c0hi.z, c0hi.w};
    const unsigned a1[8] = {c1lo.x, c1lo.y, c1lo.z, c1lo.w, c1hi.x, c1hi.y, c1hi.z, c1hi.w};
    const unsigned a2[8] = {c2lo.x, c2lo.y, c2lo.z, c2lo.w, c2hi.x, c2hi.y, c2hi.z, c2hi.w};

#pragma unroll
    for (int b = 0; b < BATCH; ++b) {
        u32x4 w;
        w.x = a0[b]; w.y = a1[b]; w.z = a2[b]; w.w = 0u;
        tab[(long long)b * NTRI + t] = w;
    }
}

// ---------------------------------------------------------------------------
// Main (unchanged from R2-verified version): 4096 blocks, one thread = 2
// quads 256 apart (coalesced 16B/lane streams, 8 px). Record gathers issued
// as ONE inline-asm block of cached global_load_dwordx4 (sc0 A/B was null:
// 92.0 vs 93.0 us — the kernel is at the random-request service floor,
// ~38 req/cyc device-wide, 1 minimal 16B request per pixel). All outputs are
// EARLY-CLOBBER (=&v) so result VGPRs can never alias a not-yet-consumed
// address pair. Block ends with s_waitcnt vmcnt(0).
// ---------------------------------------------------------------------------
__global__ __launch_bounds__(256) void raster_sc0_kernel(
    const int*   __restrict__ tids,   // [B,H,W]
    const float* __restrict__ bary,   // [B,H,W,3]
    const u32x4* __restrict__ tab,    // [B,T]
    float*       __restrict__ out)    // images [B,3,H,W] ++ alphas [B,1,H,W]
{
    const int b   = blockIdx.x & 7;              // batch slice (1 batch/XCD)
    const int blk = blockIdx.x >> 3;             // 0..511 within batch
    const int tid = (int)threadIdx.x;
    const int q0  = blk * 512 + tid;             // quad index in batch (u=0)
    const long long qg0 = (long long)b * (HWPIX / 4) + q0;

    // Coalesced cached loads: 2 x int4 tids, 6 x float4 bary
    i32x4 t4[2];
    t4[0] = ((const i32x4*)tids)[qg0];
    t4[1] = ((const i32x4*)tids)[qg0 + 256];
    f32x4 bv[6];
#pragma unroll
    for (int u = 0; u < 2; ++u)
#pragma unroll
        for (int k = 0; k < 3; ++k)
            bv[3 * u + k] = ((const f32x4*)bary)[(qg0 + u * 256) * 3 + k];

    // 8 independent cached gathers in one asm block (early-clobber outs).
    const u32x4* tbp = tab + (long long)b * NTRI;
    const u32x4* p0 = tbp + t4[0].x;
    const u32x4* p1 = tbp + t4[0].y;
    const u32x4* p2 = tbp + t4[0].z;
    const u32x4* p3 = tbp + t4[0].w;
    const u32x4* p4 = tbp + t4[1].x;
    const u32x4* p5 = tbp + t4[1].y;
    const u32x4* p6 = tbp + t4[1].z;
    const u32x4* p7 = tbp + t4[1].w;
    u32x4 r0, r1, r2, r3, r4, r5, r6, r7;
    asm volatile(
        "global_load_dwordx4 %0, %8,  off\n\t"
        "global_load_dwordx4 %1, %9,  off\n\t"
        "global_load_dwordx4 %2, %10, off\n\t"
        "global_load_dwordx4 %3, %11, off\n\t"
        "global_load_dwordx4 %4, %12, off\n\t"
        "global_load_dwordx4 %5, %13, off\n\t"
        "global_load_dwordx4 %6, %14, off\n\t"
        "global_load_dwordx4 %7, %15, off\n\t"
        "s_waitcnt vmcnt(0)"
        : "=&v"(r0), "=&v"(r1), "=&v"(r2), "=&v"(r3),
          "=&v"(r4), "=&v"(r5), "=&v"(r6), "=&v"(r7)
        : "v"(p0), "v"(p1), "v"(p2), "v"(p3),
          "v"(p4), "v"(p5), "v"(p6), "v"(p7)
        : "memory");
    const u32x4 rec[8] = {r0, r1, r2, r3, r4, r5, r6, r7};

    float* img = out + (long long)b * (3 * HWPIX);
    float* al  = out + (long long)BATCH * 3 * HWPIX + (long long)b * HWPIX;

#pragma unroll
    for (int u = 0; u < 2; ++u) {
        const f32x4 b0 = bv[3 * u + 0], b1 = bv[3 * u + 1], b2 = bv[3 * u + 2];
        const float w0[4] = {b0.x, b0.w, b1.z, b2.y};
        const float w1[4] = {b0.y, b1.x, b1.w, b2.z};
        const float w2[4] = {b0.z, b1.y, b2.x, b2.w};

        float r[4], g[4], bl[4], a[4];
#pragma unroll
        for (int i = 0; i < 4; ++i) {
            const u32x4 w = rec[4 * u + i];
            const float s0 = w0[i] * (1.0f / 255.0f);
            const float s1 = w1[i] * (1.0f / 255.0f);
            const float s2 = w2[i] * (1.0f / 255.0f);
            r[i]  = fminf(fmaxf((float)( w.x        & 0xff) * s0 +
                                (float)( w.y        & 0xff) * s1 +
                                (float)( w.z        & 0xff) * s2, 0.0f), 1.0f);
            g[i]  = fminf(fmaxf((float)((w.x >>  8) & 0xff) * s0 +
                                (float)((w.y >>  8) & 0xff) * s1 +
                                (float)((w.z >>  8) & 0xff) * s2, 0.0f), 1.0f);
            bl[i] = fminf(fmaxf((float)((w.x >> 16) & 0xff) * s0 +
                                (float)((w.y >> 16) & 0xff) * s1 +
                                (float)((w.z >> 16) & 0xff) * s2, 0.0f), 1.0f);
            a[i]  = fminf(fmaxf(2.0f * (w0[i] + w1[i] + w2[i]), 0.0f), 1.0f);
        }

        const long long s = q0 + u * 256;
        f32x4 vr = {r[0],  r[1],  r[2],  r[3]};
        f32x4 vg = {g[0],  g[1],  g[2],  g[3]};
        f32x4 vb = {bl[0], bl[1], bl[2], bl[3]};
        f32x4 va = {a[0],  a[1],  a[2],  a[3]};
        __builtin_nontemporal_store(vr, ((f32x4*)(img            )) + s);
        __builtin_nontemporal_store(vg, ((f32x4*)(img +     HWPIX)) + s);
        __builtin_nontemporal_store(vb, ((f32x4*)(img + 2 * HWPIX)) + s);
        __builtin_nontemporal_store(va, ((f32x4*)(al             )) + s);
    }
}

// ---------------------------------------------------------------------------
// Fallback: direct two-level gather (R1), used only if ws is too small.
// ---------------------------------------------------------------------------
__global__ __launch_bounds__(256) void raster_kernel(
    const int*   __restrict__ tids,
    const float* __restrict__ bary,
    const float* __restrict__ colors,
    const int*   __restrict__ tris,
    float*       __restrict__ out)
{
    const long long q  = (long long)blockIdx.x * blockDim.x + threadIdx.x;
    const long long p0 = q << 2;
    const int b  = (int)(p0 >> 20);
    const int hw = (int)(p0 & (HWPIX - 1));

    const int4 t4 = ((const int4*)tids)[q];
    const float4 bv0 = ((const float4*)bary)[q * 3 + 0];
    const float4 bv1 = ((const float4*)bary)[q * 3 + 1];
    const float4 bv2 = ((const float4*)bary)[q * 3 + 2];

    const float w0[4] = {bv0.x, bv0.w, bv1.z, bv2.y};
    const float w1[4] = {bv0.y, bv1.x, bv1.w, bv2.z};
    const float w2[4] = {bv0.z, bv1.y, bv2.x, bv2.w};
    const int  tid[4] = {t4.x, t4.y, t4.z, t4.w};

    const float* __restrict__ cb = colors + (long long)b * (3 * NVERT);

    float r[4], g[4], bl[4], a[4];
#pragma unroll
    for (int i = 0; i < 4; ++i) {
        const int t  = tid[i];
        const int v0 = tris[3 * t + 0];
        const int v1 = tris[3 * t + 1];
        const int v2 = tris[3 * t + 2];
        const float* c0 = cb + 3 * v0;
        const float* c1 = cb + 3 * v1;
        const float* c2 = cb + 3 * v2;
        const float u0 = w0[i], u1 = w1[i], u2 = w2[i];
        r[i]  = fminf(fmaxf(c0[0] * u0 + c1[0] * u1 + c2[0] * u2, 0.0f), 1.0f);
        g[i]  = fminf(fmaxf(c0[1] * u0 + c1[1] * u1 + c2[1] * u2, 0.0f), 1.0f);
        bl[i] = fminf(fmaxf(c0[2] * u0 + c1[2] * u1 + c2[2] * u2, 0.0f), 1.0f);
        a[i]  = fminf(fmaxf(2.0f * (u0 + u1 + u2), 0.0f), 1.0f);
    }

    float* img = out + (long long)b * (3 * HWPIX) + hw;
    ((float4*)(img            ))[0] = make_float4(r[0],  r[1],  r[2],  r[3]);
    ((float4*)(img +     HWPIX))[0] = make_float4(g[0],  g[1],  g[2],  g[3]);
    ((float4*)(img + 2 * HWPIX))[0] = make_float4(bl[0], bl[1], bl[2], bl[3]);

    float* al = out + (long long)BATCH * 3 * HWPIX + (long long)b * HWPIX + hw;
    ((float4*)al)[0] = make_float4(a[0], a[1], a[2], a[3]);
}

extern "C" void kernel_launch(void* const* d_in, const int* in_sizes, int n_in,
                              void* d_out, int out_size, void* d_ws, size_t ws_size,
                              hipStream_t stream) {
    const int*   tids   = (const int*)  d_in[0];
    const float* bary   = (const float*)d_in[1];
    const float* colors = (const float*)d_in[2];
    const int*   tris   = (const int*)  d_in[3];
    float*       out    = (float*)      d_out;

    const size_t tab_bytes  = (size_t)BATCH * NTRI * sizeof(u32x4);   // ~9.06 MB
    const size_t ctab_bytes = (size_t)NVERT * 8 * sizeof(unsigned);   // ~1.14 MB

    if (ws_size >= tab_bytes + ctab_bytes) {
        u32x4* tab    = (u32x4*)d_ws;
        u32x4* ctab_t = (u32x4*)((char*)d_ws + tab_bytes);

        quant_colors_t<<<(NVERT + 255) / 256, 256, 0, stream>>>(colors, ctab_t);
        build_tab_t<<<(NTRI + 255) / 256, 256, 0, stream>>>(tris, ctab_t, tab);

        const int grid = (BATCH * HWPIX) / (8 * 256);   // 4096 blocks
        raster_sc0_kernel<<<grid, 256, 0, stream>>>(tids, bary, tab, out);
    } else {
        const int quads = (BATCH * HWPIX) / 4;
        raster_kernel<<<quads / 256, 256, 0, stream>>>(tids, bary, colors, tris, out);
    }
}